// Round 5
// baseline (197.684 us; speedup 1.0000x reference)
//
#include <hip/hip_runtime.h>

// MRConv: B=4, C=192, N=10000, K=16, OUT=384
// out[b,o,n] = relu( sum_ch W[o,ch]*feat[b,ch,n] + bias[o] )
// feat[b,2c,n] = x[b,c,n]; feat[b,2c+1,n] = max_k( x[b,c,e0[b,n,k]] - x[b,c,e1[b,n,k]] )
//
// Round 5: latency-hiding fixes. Batched register gather (32 uint2 loads in
// flight, explicit arrays), nontemporal out/eidx (keep xT L2-resident),
// masked LDS stores (kill same-address write conflicts), 4 blocks/CU.

#define NB   4
#define NC   192
#define NN   10000
#define NK   16
#define NOUT 384
#define K2C  384            // 2*C

typedef _Float16 f16x8 __attribute__((ext_vector_type(8)));  // 4 VGPRs (MFMA A/B)
typedef _Float16 h2    __attribute__((ext_vector_type(2)));  // packed pair
typedef float    f32x4 __attribute__((ext_vector_type(4)));

__device__ inline unsigned short f2h(float f) {
    _Float16 h = (_Float16)f;
    return __builtin_bit_cast(unsigned short, h);
}
__device__ inline h2 hlo(unsigned int u) { return __builtin_bit_cast(h2, (unsigned int)(u & 0xFFFFu)); }

// ---------------- K1: transpose x[b][c][n] f32 -> xT[b][n][c] f16, + W -> f16 ----------------
__global__ __launch_bounds__(256) void k_prep(const float* __restrict__ x,
                                              const float* __restrict__ w,
                                              unsigned short* __restrict__ xT,
                                              unsigned short* __restrict__ wh) {
    __shared__ unsigned short tile[NC * 65];   // 192 x 64 (+1 pad)
    int gid = blockIdx.x * 256 + threadIdx.x;
    if (gid < NOUT * K2C) wh[gid] = f2h(w[gid]);       // 147456 elems

    int b  = blockIdx.x & 3;
    int nb = (blockIdx.x >> 2) * 64;
    int t  = threadIdx.x;
    const float* xb = x + (size_t)b * NC * NN;
    for (int i = 0; i < 48; ++i) {             // 192*64/256
        int idx = i * 256 + t;
        int c  = idx >> 6;
        int nl = idx & 63;
        int n  = nb + nl;
        float v = (n < NN) ? xb[(size_t)c * NN + n] : 0.f;   // coalesced along n
        tile[c * 65 + nl] = f2h(v);
    }
    __syncthreads();
    unsigned int* xTd = (unsigned int*)(xT + (size_t)b * NN * NC);  // 96 dwords / node row
    for (int i = 0; i < 24; ++i) {             // 96*64/256 packed-dword writes
        int idx = i * 256 + t;
        int nl  = idx / 96;
        int cd  = idx - nl * 96;               // dword = channels {2cd, 2cd+1}
        int n   = nb + nl;
        if (n < NN) {
            unsigned int lo = tile[(2 * cd)     * 65 + nl];
            unsigned int hi = tile[(2 * cd + 1) * 65 + nl];
            xTd[(size_t)n * 96 + cd] = lo | (hi << 16);    // coalesced along cd
        }
    }
}

// ---------------- K2: fused gather+max -> LDS -> MFMA GEMM ----------------
// Block = 32 nodes x 384 outs, 4 waves. grid 4*313 = 1252 (~4.9 blocks/CU).
// LDS: 32 rows x 49 granules x 16B = 25088 B (stride 49: b128 reads across
// rows conflict-free; writes consecutive-granule, lanes>=48 masked off).
// Phase 1: wave owns 8 nodes. Per node: ALL 16 j-rows + 16 i-rows loaded into
//   register arrays first (32 uint2 loads outstanding), then packed f16
//   sub+max. Edge indices via readlane (SGPR saddr + fixed voffset).
// Phase 2: wave tile 96 out x 32 n = 6x2 frags of mfma_f32_16x16x32_f16;
//   A = W f16 direct from L2. Output stores nontemporal (don't evict xT).
__global__ __launch_bounds__(256, 4) void k_fused(const unsigned short* __restrict__ wh,
                                                  const unsigned short* __restrict__ xT,
                                                  const int* __restrict__ eidx,
                                                  const float* __restrict__ bias,
                                                  float* __restrict__ out) {
    __shared__ unsigned short lds[32 * 49 * 8];   // 25088 B
    int bid  = blockIdx.x;
    int b    = bid & 3;                            // batch -> XCD pair {b, b+4}
    int nt   = bid >> 2;                           // 0..312
    int wv   = threadIdx.x >> 6;
    int lane = threadIdx.x & 63;

    const uint2* xr2 = (const uint2*)(xT + (size_t)b * NN * NC);   // 48 uint2 / node row
    const int* e0 = eidx + (size_t)b * NN * NK;                    // neighbors (x_j)
    const int* e1 = eidx + (size_t)NB * NN * NK + (size_t)b * NN * NK;  // centers (x_i)
    int nbase = nt * 32 + wv * 8;

    // ---- edge indices for the wave's 8 nodes (nontemporal: read-once stream) ----
    int ej[2], ei[2];
#pragma unroll
    for (int i = 0; i < 2; ++i) {
        int idx = i * 64 + lane;
        int nn  = nbase + (idx >> 4);
        ej[i] = (nn < NN) ? __builtin_nontemporal_load(&e0[(size_t)nbase * NK + idx]) : 0;
        ei[i] = (nn < NN) ? __builtin_nontemporal_load(&e1[(size_t)nbase * NK + idx]) : 0;
    }
    int dc  = (lane < 48) ? lane : 47;             // clamped granule id for loads
    bool wr = (lane < 48);                         // store mask

#pragma unroll 1
    for (int it = 0; it < 8; ++it) {               // one node per iteration
        int n = nbase + it;
        if (n < NN) {                              // wave-uniform
            int nl = wv * 8 + it;
            // ---- batch-issue all 33 row loads (explicit register arrays) ----
            uint2 jr[16], ir[16];
#pragma unroll
            for (int k = 0; k < 16; ++k) {
                int j = __builtin_amdgcn_readlane(ej[it >> 2], ((it & 3) * 16) + k);
                jr[k] = xr2[(size_t)j * 48 + dc];
            }
#pragma unroll
            for (int k = 0; k < 16; ++k) {
                int i_ = __builtin_amdgcn_readlane(ei[it >> 2], ((it & 3) * 16) + k);
                ir[k] = xr2[(size_t)i_ * 48 + dc];
            }
            uint2 cx = xr2[(size_t)n * 48 + dc];   // center row, ch 4dc..4dc+3
            // ---- packed f16 reduce ----
            h2 m0 = __builtin_bit_cast(h2, 0xFC00FC00u);   // (-inf, -inf)
            h2 m1 = m0;
#pragma unroll
            for (int k = 0; k < 16; ++k) {
                h2 dlo = __builtin_bit_cast(h2, jr[k].x) - __builtin_bit_cast(h2, ir[k].x);
                h2 dhi = __builtin_bit_cast(h2, jr[k].y) - __builtin_bit_cast(h2, ir[k].y);
                m0 = __builtin_elementwise_max(m0, dlo);   // v_pk_max_f16
                m1 = __builtin_elementwise_max(m1, dhi);
            }
            unsigned int mb0 = __builtin_bit_cast(unsigned int, m0);
            unsigned int mb1 = __builtin_bit_cast(unsigned int, m1);
            // granule = interleaved (x_c, m_c) for ch 4dc..4dc+3
            uint4 g;
            g.x = (cx.x & 0xFFFFu) | (mb0 << 16);
            g.y = (cx.x >> 16)     | (mb0 & 0xFFFF0000u);
            g.z = (cx.y & 0xFFFFu) | (mb1 << 16);
            g.w = (cx.y >> 16)     | (mb1 & 0xFFFF0000u);
            if (wr) *(uint4*)&lds[(size_t)(nl * 49 + dc) * 8] = g;
        }
    }

    // ---- MFMA phase: 6x2 frags of 16x16x32 f16 ----
    int r = lane & 15;
    int q = lane >> 4;
    const unsigned short* aptr = wh + (size_t)(wv * 96 + r) * K2C + q * 8;
    f32x4 acc[6][2];
#pragma unroll
    for (int mi = 0; mi < 6; ++mi)
#pragma unroll
        for (int ni = 0; ni < 2; ++ni)
            acc[mi][ni] = (f32x4){0.f, 0.f, 0.f, 0.f};

    __syncthreads();

#pragma unroll 2
    for (int t = 0; t < 12; ++t) {
        f16x8 a[6], bb[2];
#pragma unroll
        for (int mi = 0; mi < 6; ++mi)
            a[mi] = *(const f16x8*)(aptr + (size_t)mi * 16 * K2C + t * 32);
#pragma unroll
        for (int ni = 0; ni < 2; ++ni) {
            int row = ni * 16 + r;
            bb[ni] = *(const f16x8*)&lds[(size_t)(row * 49 + 4 * t + q) * 8];
        }
#pragma unroll
        for (int mi = 0; mi < 6; ++mi)
#pragma unroll
            for (int ni = 0; ni < 2; ++ni)
                acc[mi][ni] = __builtin_amdgcn_mfma_f32_16x16x32_f16(a[mi], bb[ni], acc[mi][ni], 0, 0, 0);
    }

    float* ob = out + (size_t)b * NOUT * NN;
#pragma unroll
    for (int mi = 0; mi < 6; ++mi) {
        int obase = wv * 96 + mi * 16 + q * 4;
        float4 b4 = *(const float4*)(bias + obase);   // 16B-aligned
        float bv[4] = {b4.x, b4.y, b4.z, b4.w};
#pragma unroll
        for (int ni = 0; ni < 2; ++ni) {
            int n = nt * 32 + ni * 16 + r;
            if (n < NN) {
#pragma unroll
                for (int rr = 0; rr < 4; ++rr) {
                    float val = fmaxf(acc[mi][ni][rr] + bv[rr], 0.f);
                    __builtin_nontemporal_store(val, &ob[(size_t)(obase + rr) * NN + n]);
                }
            }
        }
    }
}

extern "C" void kernel_launch(void* const* d_in, const int* in_sizes, int n_in,
                              void* d_out, int out_size, void* d_ws, size_t ws_size,
                              hipStream_t stream) {
    const float* x    = (const float*)d_in[0];   // [4,192,10000,1]
    const int*   eidx = (const int*)d_in[1];     // [2,4,10000,16]
    const float* w    = (const float*)d_in[2];   // [384,384]
    const float* bias = (const float*)d_in[3];   // [384]
    float* out = (float*)d_out;                  // [4,384,10000,1,1]

    // workspace: xT [4][10000][192] f16 (15.36 MB) | wh [384][384] f16 (0.29 MB)
    unsigned short* xT = (unsigned short*)d_ws;
    unsigned short* wh = xT + (size_t)NB * NN * NC;

    hipLaunchKernelGGL(k_prep,  dim3(4 * 157), dim3(256), 0, stream, x, w, xT, wh);
    hipLaunchKernelGGL(k_fused, dim3(4 * 313), dim3(256), 0, stream, wh, xT, eidx, bias, out);
}